// Round 6
// baseline (300.779 us; speedup 1.0000x reference)
//
#include <hip/hip_runtime.h>
#include <hip/hip_bf16.h>
#include <stdint.h>

#define NE    64
#define DIN   512
#define DOUT  512
#define TTOK  131072
#define BM    128
#define BN    128
#define BK    32
#define NK    (DIN / BK)              // 16 K-steps
#define TILES_TOTAL (TTOK / BM + NE)  // 1088
#define NXCD  8
#define TPX   (TILES_TOTAL / NXCD)    // 136

typedef __bf16 bf16x8_t __attribute__((ext_vector_type(8)));
typedef float  f32x4_t  __attribute__((ext_vector_type(4)));

// LDS (80 KB total -> exactly 2 blocks/CU):
//   A ring: 3 x 16384  (128 rows x 128B fp32, source-preswizzled, (row&7) XOR)
//   B dbuf: 2 x 16384  (128 rows x 128B bf16 = K-step PAIR, (row&7) XOR)
#define ABUF(i) ((i) * 16384)
#define BBUF(i) (49152 + (i) * 16384)
#define LDS_BYTES 81920

#define WAITV(n) asm volatile("s_waitcnt vmcnt(" #n ")" ::: "memory")
#define WAITVL(n) asm volatile("s_waitcnt vmcnt(" #n ") lgkmcnt(0)" ::: "memory")
#define SB() __builtin_amdgcn_sched_barrier(0)

// ws layout: ws[0] = ntiles; tile table at ws+4 (int4: e, row0, row_end, pad)
__global__ void setup_tiles(const int* __restrict__ cnt, int* __restrict__ ws) {
    int e = threadIdx.x;
    if (e >= NE) return;
    int off = 0, tbase = 0;
    for (int i = 0; i < e; ++i) {
        int c = cnt[i];
        off += c;
        tbase += (c + (BM - 1)) / BM;
    }
    int c = cnt[e];
    int nt = (c + (BM - 1)) / BM;
    int* tbl = ws + 4;
    for (int t = 0; t < nt; ++t) {
        int idx = tbase + t;
        tbl[4 * idx + 0] = e;
        tbl[4 * idx + 1] = off + t * BM;
        tbl[4 * idx + 2] = off + c;
        tbl[4 * idx + 3] = 0;
    }
    if (e == NE - 1) ws[0] = tbase + nt;
}

__device__ __forceinline__ void gload16(const float* g, uint8_t* l) {
    __builtin_amdgcn_global_load_lds(
        (const __attribute__((address_space(1))) uint32_t*)g,
        (__attribute__((address_space(3))) uint32_t*)l, 16, 0, 0);
}

__global__ __launch_bounds__(256, 2) void moe_gemm(
    const float* __restrict__ inp,
    const float* __restrict__ weight,
    const float* __restrict__ bias,
    const int* __restrict__ ws,
    float* __restrict__ out)
{
    __shared__ __align__(16) uint8_t smem[LDS_BYTES];

    const int bid  = blockIdx.x;
    const int xcd  = bid & (NXCD - 1);
    const int slot = bid >> 3;
    const int tile = xcd * TPX + (slot >> 2);
    const int n0   = (slot & 3) * BN;

    const int ntiles = ws[0];
    if (tile >= ntiles) return;
    const int4 ti = ((const int4*)(ws + 4))[tile];
    const int e = ti.x, row0 = ti.y, row_end = ti.z;

    const int tid  = threadIdx.x;
    const int lane = tid & 63;
    const int wave = tid >> 6;

    // ---- A staging via global_load_lds (fp32, source-preswizzled) ----
    // wave covers rows [wave*32, wave*32+32): 4 gload16, each = 8 rows x 128B.
    // LDS chunk c of row R holds global chunk c ^ (R&7); group base % 8 == 0.
    const int dr = lane >> 3;
    const int ac = lane & 7;
    const float* asrc[4];
#pragma unroll
    for (int i = 0; i < 4; ++i) {
        int arow = wave * 32 + i * 8 + dr;
        int grow = row0 + arow;
        if (grow > row_end - 1) grow = row_end - 1;   // clamp (C-stores guarded)
        asrc[i] = inp + (size_t)grow * DIN + ((ac ^ dr) << 2);
    }
    auto issueA = [&](int kk, int buf) {
        uint8_t* dst = smem + ABUF(buf) + wave * 4096;
#pragma unroll
        for (int i = 0; i < 4; ++i)
            gload16(asrc[i] + kk * BK, dst + i * 1024);
    };

    // ---- B staging: K-step PAIRS (K=64 per row -> 128B rows, (row&7) XOR) ----
    // thread (brow = tid>>1, bh = tid&1): loads 32 fp32 = k-range
    // [(P*2+bh)*32, +32) of row brow; writes 4 x bf16x8 (ds_write_b128).
    const int brow = tid >> 1;
    const int bh   = tid & 1;
    const float* bsrc = weight + (size_t)e * (DOUT * DIN)
                        + (size_t)(n0 + brow) * DIN + bh * BK;
    const int bsw = (brow & 7) << 4;
    f32x4_t rb[2][8];

    auto issueB = [&](int P) {            // P compile-time (full unroll)
        const float* p = bsrc + P * 2 * BK;
#pragma unroll
        for (int c = 0; c < 8; ++c)
            rb[P & 1][c] = *(const f32x4_t*)(p + c * 4);
    };
    auto writeB = [&](int P) {
#pragma unroll
        for (int c2 = 0; c2 < 4; ++c2) {
            bf16x8_t h;
#pragma unroll
            for (int j = 0; j < 4; ++j) {
                h[j]     = (__bf16)rb[P & 1][2 * c2][j];
                h[4 + j] = (__bf16)rb[P & 1][2 * c2 + 1][j];
            }
            *(bf16x8_t*)(smem + BBUF(P & 1) + brow * 128 +
                         ((bh * 64 + c2 * 16) ^ bsw)) = h;
        }
    };

    // ---- compute ----
    const int wr = (wave >> 1) * 64;
    const int wc = (wave & 1) * 64;
    const int frow = lane & 15;
    const int kg   = lane >> 4;

    f32x4_t acc[4][4] = {};

    auto compute = [&](int abuf, int bb, int p) {
        bf16x8_t af[4], bg[4];
#pragma unroll
        for (int m = 0; m < 4; ++m) {
            const int row = wr + m * 16 + frow;
            const uint8_t* pa = smem + ABUF(abuf) + row * 128;
            const int sw = (row & 7) << 4;
            f32x4_t q0 = *(const f32x4_t*)(pa + ((kg * 32)      ^ sw));
            f32x4_t q1 = *(const f32x4_t*)(pa + ((kg * 32 + 16) ^ sw));
#pragma unroll
            for (int j = 0; j < 4; ++j) {
                af[m][j]     = (__bf16)q0[j];
                af[m][4 + j] = (__bf16)q1[j];
            }
        }
#pragma unroll
        for (int n = 0; n < 4; ++n) {
            const int row = wc + n * 16 + frow;
            bg[n] = *(const bf16x8_t*)(smem + BBUF(bb) + row * 128 +
                                       ((p * 64 + kg * 16) ^ ((row & 7) << 4)));
        }
        __builtin_amdgcn_s_setprio(1);
#pragma unroll
        for (int m = 0; m < 4; ++m)
#pragma unroll
            for (int n = 0; n < 4; ++n)
                acc[m][n] = __builtin_amdgcn_mfma_f32_16x16x32_bf16(
                    af[m], bg[n], acc[m][n], 0, 0, 0);
        __builtin_amdgcn_s_setprio(0);
    };

    // ---- prologue: order pinned with sched_barrier so the explicit
    // vmcnt(12) provably drains B0+A(0) while keeping A(1)+B1 in flight ----
    issueB(0);  SB();
    issueA(0, 0); SB();
    issueA(1, 1); SB();
    issueB(1);  SB();
    writeB(0);                       // auto-wait drains B0
    WAITVL(12); SB();                // drain A(0); A(1)[4]+B1[8] fly on
    __builtin_amdgcn_s_barrier();

    // ---- main loop, fully unrolled; per-step waits are compile-time ----
    // odd k:  WAITV(12) leaves A(k+2)[4]+Bpair[8], drains A(k+1) (oldest)
    // even k: writeB auto-drains its pair; WAITVL(4) leaves A(k+2), drains A(k+1)
#pragma unroll
    for (int k = 0; k < NK; ++k) {
        if (k + 2 < NK) issueA(k + 2, (k + 2) % 3);
        if ((k & 1) && k <= 11) issueB((k + 3) / 2);
        compute(k % 3, (k >> 1) & 1, k & 1);
        if (!(k & 1)) {
            if (k + 2 < NK) {                 // even, k <= 12
                writeB((k + 2) / 2);
                WAITVL(4); SB();
                __builtin_amdgcn_s_barrier();
            } else if (k == 14) {
                WAITV(0); SB();               // drain A(15)
                __builtin_amdgcn_s_barrier();
            }
        } else if (k < NK - 1) {
            if (k <= 11) { WAITV(12); SB(); }
            else        { WAITV(4);  SB(); }  // k == 13: drain A(14), keep A(15)
            __builtin_amdgcn_s_barrier();
        }
    }

    // ---- epilogue: C/D layout col = lane&15, row = (lane>>4)*4 + j [m89] ----
    const int crow = kg * 4;
    const int ccol = frow;
    float bv[4];
#pragma unroll
    for (int n = 0; n < 4; ++n)
        bv[n] = bias[e * DOUT + n0 + wc + n * 16 + ccol];
#pragma unroll
    for (int m = 0; m < 4; ++m) {
#pragma unroll
        for (int j = 0; j < 4; ++j) {
            const int grow = row0 + wr + m * 16 + crow + j;
            if (grow < row_end) {
                float* orow = out + (size_t)grow * DOUT + n0 + wc + ccol;
#pragma unroll
                for (int n = 0; n < 4; ++n)
                    orow[n * 16] = acc[m][n][j] + bv[n];
            }
        }
    }
}

extern "C" void kernel_launch(void* const* d_in, const int* in_sizes, int n_in,
                              void* d_out, int out_size, void* d_ws, size_t ws_size,
                              hipStream_t stream) {
    const float* inp    = (const float*)d_in[0];
    const float* weight = (const float*)d_in[1];
    const float* bias   = (const float*)d_in[2];
    const int* cnt      = (const int*)d_in[3];   // int64 in reference, delivered as int32
    float* out = (float*)d_out;
    int* ws = (int*)d_ws;

    hipLaunchKernelGGL(setup_tiles, dim3(1), dim3(64), 0, stream, cnt, ws);
    hipLaunchKernelGGL(moe_gemm, dim3(TILES_TOTAL * 4), dim3(256), 0, stream,
                       inp, weight, bias, ws, out);
}

// Round 7
// 221.988 us; speedup vs baseline: 1.3549x; 1.3549x over previous
//
#include <hip/hip_runtime.h>
#include <hip/hip_bf16.h>
#include <stdint.h>

#define NE    64
#define DIN   512
#define DOUT  512
#define TTOK  131072
#define BM    128
#define BN    128
#define BK    32
#define NK    (DIN / BK)              // 16 K-steps
#define TILES_TOTAL (TTOK / BM + NE)  // 1088
#define NXCD  8
#define TPX   (TILES_TOTAL / NXCD)    // 136

typedef __bf16 bf16x8_t __attribute__((ext_vector_type(8)));
typedef float  f32x4_t  __attribute__((ext_vector_type(4)));

// LDS (48 KB total -> 3 blocks/CU = 12 waves/CU):
//   A dbuf: 2 x 16384  (128 rows x 128B fp32 = 32 k; source-preswizzled (row&7))
//   B dbuf: 2 x 8192   (64 LDS rows x 128B bf16; row lr holds dout rows lr and
//                       lr+64, 32 k each; same (lr&7) XOR swizzle)
#define ABUF(i) ((i) * 16384)
#define BBUF(i) (32768 + (i) * 8192)
#define LDS_BYTES 49152

#define WAITV0() asm volatile("s_waitcnt vmcnt(0)" ::: "memory")
#define SB() __builtin_amdgcn_sched_barrier(0)

// ws layout: ws[0] = ntiles; tile table (int4) at ws+4; bf16 weight at +32KB
#define WBF_OFF 32768

__global__ void setup_tiles(const int* __restrict__ cnt, int* __restrict__ ws) {
    int e = threadIdx.x;
    if (e >= NE) return;
    int off = 0, tbase = 0;
    for (int i = 0; i < e; ++i) {
        int c = cnt[i];
        off += c;
        tbase += (c + (BM - 1)) / BM;
    }
    int c = cnt[e];
    int nt = (c + (BM - 1)) / BM;
    int* tbl = ws + 4;
    for (int t = 0; t < nt; ++t) {
        int idx = tbase + t;
        tbl[4 * idx + 0] = e;
        tbl[4 * idx + 1] = off + t * BM;
        tbl[4 * idx + 2] = off + c;
        tbl[4 * idx + 3] = 0;
    }
    if (e == NE - 1) ws[0] = tbase + nt;
}

// weight fp32 -> bf16, streaming (16.78M elems, 8 per thread-iter)
__global__ __launch_bounds__(256) void wcvt(const float* __restrict__ w,
                                            __bf16* __restrict__ wbf) {
    const size_t stride = (size_t)gridDim.x * 256;
    size_t i = (size_t)blockIdx.x * 256 + threadIdx.x;
    const size_t n8 = (size_t)NE * DOUT * DIN / 8;
    for (; i < n8; i += stride) {
        f32x4_t a = *(const f32x4_t*)(w + i * 8);
        f32x4_t b = *(const f32x4_t*)(w + i * 8 + 4);
        bf16x8_t h;
#pragma unroll
        for (int j = 0; j < 4; ++j) {
            h[j]     = (__bf16)a[j];
            h[4 + j] = (__bf16)b[j];
        }
        *(bf16x8_t*)(wbf + i * 8) = h;
    }
}

__device__ __forceinline__ void gload16(const void* g, uint8_t* l) {
    __builtin_amdgcn_global_load_lds(
        (const __attribute__((address_space(1))) uint32_t*)g,
        (__attribute__((address_space(3))) uint32_t*)l, 16, 0, 0);
}

__global__ __launch_bounds__(256, 3) void moe_gemm(
    const float* __restrict__ inp,
    const __bf16* __restrict__ wbf,
    const float* __restrict__ bias,
    const int* __restrict__ ws,
    float* __restrict__ out)
{
    __shared__ __align__(16) uint8_t smem[LDS_BYTES];

    const int bid  = blockIdx.x;
    const int xcd  = bid & (NXCD - 1);
    const int slot = bid >> 3;
    const int tile = xcd * TPX + (slot >> 2);
    const int n0   = (slot & 3) * BN;

    const int ntiles = ws[0];
    if (tile >= ntiles) return;
    const int4 ti = ((const int4*)(ws + 4))[tile];
    const int e = ti.x, row0 = ti.y, row_end = ti.z;

    const int tid  = threadIdx.x;
    const int lane = tid & 63;
    const int wave = tid >> 6;
    const int dr = lane >> 3;          // row-in-8-group
    const int ac = lane & 7;           // dest 16B chunk (linear)
    const int u  = ac ^ dr;            // logical chunk (group base % 8 == 0)

    // ---- A staging: 4 gload16/wave, each 8 rows x 128B, source-preswizzled ----
    const float* asrc[4];
#pragma unroll
    for (int i = 0; i < 4; ++i) {
        int arow = wave * 32 + i * 8 + dr;
        int grow = row0 + arow;
        if (grow > row_end - 1) grow = row_end - 1;   // clamp (C-stores guarded)
        asrc[i] = inp + (size_t)grow * DIN + (u << 2);
    }
    auto issueA = [&](int t, int buf) {
        uint8_t* dst = smem + ABUF(buf) + wave * 4096;
#pragma unroll
        for (int i = 0; i < 4; ++i)
            gload16(asrc[i] + t * BK, dst + i * 1024);
    };

    // ---- B staging: 2 gload16/wave. LDS row lr (0..63) chunk-logical u:
    //   u<4 -> dout n0+lr,   k-part u&3
    //   u>=4 -> dout n0+lr+64, k-part u&3
    // (16B = 8 bf16 = k[(u&3)*8 .. +8) of the 32-k step) ----
    const __bf16* bsrc[2];
#pragma unroll
    for (int i = 0; i < 2; ++i) {
        int lr = wave * 16 + i * 8 + dr;
        int dout = n0 + lr + ((u >> 2) << 6);
        bsrc[i] = wbf + (size_t)(e * DOUT + dout) * DIN + (u & 3) * 8;
    }
    auto issueB = [&](int t, int buf) {
        uint8_t* dst = smem + BBUF(buf) + wave * 2048;
#pragma unroll
        for (int i = 0; i < 2; ++i)
            gload16(bsrc[i] + t * BK, dst + i * 1024);
    };

    // ---- compute ----
    const int wr = (wave >> 1) * 64;
    const int wc = (wave & 1) * 64;
    const int frow = lane & 15;
    const int kg   = lane >> 4;        // 0..3: which 8-k group of the 32-k step

    f32x4_t acc[4][4] = {};

    auto compute = [&](int buf) {
        bf16x8_t af[4], bg[4];
#pragma unroll
        for (int m = 0; m < 4; ++m) {
            const int row = wr + m * 16 + frow;
            const uint8_t* pa = smem + ABUF(buf) + row * 128;
            const int sw = (row & 7) << 4;
            f32x4_t q0 = *(const f32x4_t*)(pa + ((kg * 32)      ^ sw));
            f32x4_t q1 = *(const f32x4_t*)(pa + ((kg * 32 + 16) ^ sw));
#pragma unroll
            for (int j = 0; j < 4; ++j) {
                af[m][j]     = (__bf16)q0[j];
                af[m][4 + j] = (__bf16)q1[j];
            }
        }
#pragma unroll
        for (int n = 0; n < 4; ++n) {
            const int row = wc + n * 16 + frow;     // dout-row in tile (0..127)
            const int lr  = row & 63;
            const int h   = row >> 6;
            bg[n] = *(const bf16x8_t*)(smem + BBUF(buf) + lr * 128 +
                                       ((h * 64 + kg * 16) ^ ((lr & 7) << 4)));
        }
        __builtin_amdgcn_s_setprio(1);
#pragma unroll
        for (int m = 0; m < 4; ++m)
#pragma unroll
            for (int n = 0; n < 4; ++n)
                acc[m][n] = __builtin_amdgcn_mfma_f32_16x16x32_bf16(
                    af[m], bg[n], acc[m][n], 0, 0, 0);
        __builtin_amdgcn_s_setprio(0);
    };

    // ---- T3-minimal 2-phase: stage(t+1) -> compute(t) -> vmcnt(0)+barrier.
    // No ds_writes in-loop, so no lgkmcnt discipline needed at barriers. ----
    issueA(0, 0);
    issueB(0, 0);
    WAITV0(); SB();
    __builtin_amdgcn_s_barrier();
#pragma unroll
    for (int t = 0; t < NK; ++t) {
        const int buf = t & 1;
        if (t + 1 < NK) {
            issueA(t + 1, buf ^ 1);
            issueB(t + 1, buf ^ 1);
        }
        compute(buf);
        if (t + 1 < NK) {
            WAITV0(); SB();
            __builtin_amdgcn_s_barrier();
        }
    }

    // ---- epilogue: C/D layout col = lane&15, row = (lane>>4)*4 + j [m89] ----
    const int crow = kg * 4;
    const int ccol = frow;
    float bv[4];
#pragma unroll
    for (int n = 0; n < 4; ++n)
        bv[n] = bias[e * DOUT + n0 + wc + n * 16 + ccol];
#pragma unroll
    for (int m = 0; m < 4; ++m) {
#pragma unroll
        for (int j = 0; j < 4; ++j) {
            const int grow = row0 + wr + m * 16 + crow + j;
            if (grow < row_end) {
                float* orow = out + (size_t)grow * DOUT + n0 + wc + ccol;
#pragma unroll
                for (int n = 0; n < 4; ++n)
                    orow[n * 16] = acc[m][n][j] + bv[n];
            }
        }
    }
}

extern "C" void kernel_launch(void* const* d_in, const int* in_sizes, int n_in,
                              void* d_out, int out_size, void* d_ws, size_t ws_size,
                              hipStream_t stream) {
    const float* inp    = (const float*)d_in[0];
    const float* weight = (const float*)d_in[1];
    const float* bias   = (const float*)d_in[2];
    const int* cnt      = (const int*)d_in[3];   // int64 in reference, delivered as int32
    float* out = (float*)d_out;
    int* ws = (int*)d_ws;
    __bf16* wbf = (__bf16*)((char*)d_ws + WBF_OFF);

    hipLaunchKernelGGL(setup_tiles, dim3(1), dim3(64), 0, stream, cnt, ws);
    hipLaunchKernelGGL(wcvt, dim3(2048), dim3(256), 0, stream, weight, wbf);
    hipLaunchKernelGGL(moe_gemm, dim3(TILES_TOTAL * 4), dim3(256), 0, stream,
                       inp, wbf, bias, ws, out);
}